// Round 4
// baseline (343.152 us; speedup 1.0000x reference)
//
#include <hip/hip_runtime.h>
#include <hip/hip_bf16.h>
#include <math.h>

// MLPTexture3D: 5-level dense-grid trilinear encoding + MLP 10->32->32->3
// via v_mfma_f32_32x32x16_bf16 (64 points/wave).
//
// Round-4: kernel is bound by scattered-gather LINE-REQUEST rate (rounds 1-3
// all ~200us regardless of VALU/instr count). Fixes:
//   - levels 0+1 staged in LDS as packed bf16 (74.9KB/block, -40% requests)
//   - whole table converted to packed bf16 in d_ws (2.13MB -> L2-resident)
//   - nontemporal texc/out streams (stop washing the table out of L2)

namespace {

typedef __attribute__((ext_vector_type(8)))  short short8;
typedef __attribute__((ext_vector_type(16))) float f32x16;
typedef __attribute__((ext_vector_type(4), aligned(8))) float f32x4a;
typedef __attribute__((ext_vector_type(2), aligned(4))) unsigned int u32x2a;

union S8 { short8 v; int d[4]; };

#define SWAP32(a, b) asm volatile("v_permlane32_swap_b32 %0, %1" : "+v"(a), "+v"(b))

constexpr int NTAB   = 533601;   // total table entries
constexpr int NSTAGE = 18737;    // entries in levels 0+1 (OFFS[2])

__device__ __forceinline__ int cvt_pk(float lo, float hi) {
    int d;
    asm("v_cvt_pk_bf16_f32 %0, %1, %2" : "=v"(d) : "v"(lo), "v"(hi));
    return d;
}

__device__ __forceinline__ short8 pack8(float4 a, float4 b) {
    S8 u;
    u.d[0] = cvt_pk(a.x, a.y);
    u.d[1] = cvt_pk(a.z, a.w);
    u.d[2] = cvt_pk(b.x, b.y);
    u.d[3] = cvt_pk(b.z, b.w);
    return u.v;
}

__device__ __forceinline__ float clamp01(float v) {
    return fminf(fmaxf(v, 0.0f), 1.0f);
}

// unpack packed bf16 pair (low16 = feat0, high16 = feat1)
__device__ __forceinline__ float2 upk(unsigned int u) {
    float2 r;
    r.x = __uint_as_float(u << 16);
    r.y = __uint_as_float(u & 0xffff0000u);
    return r;
}

__device__ __forceinline__ float4 pair_lds(const unsigned int* l, int idx) {
    float2 a = upk(l[idx]);
    float2 b = upk(l[idx + 1]);
    return make_float4(a.x, a.y, b.x, b.y);
}

__device__ __forceinline__ float4 pair_ws(const unsigned int* w, int idx) {
    u32x2a u = *reinterpret_cast<const u32x2a*>(w + idx);
    float2 a = upk(u.x);
    float2 b = upk(u.y);
    return make_float4(a.x, a.y, b.x, b.y);
}

__device__ __forceinline__ float4 pair_f32(const float2* t, int idx) {
    f32x4a q = *reinterpret_cast<const f32x4a*>(t + idx);
    return make_float4(q[0], q[1], q[2], q[3]);
}

// q** ordering: (z0.f0, z0.f1, z1.f0, z1.f1) for corners (y,x) = 00,01,10,11
__device__ __forceinline__ float2 trilerp(float tx, float ty, float tz,
        float4 q00, float4 q01, float4 q10, float4 q11) {
    float sx = 1.0f - tx, sy = 1.0f - ty, sz = 1.0f - tz;
    float w00 = sy*sz, w01 = sy*tz, w10 = ty*sz, w11 = ty*tz;
    float a00 = sx*w00, a01 = sx*w01, a10 = sx*w10, a11 = sx*w11;
    float b00 = tx*w00, b01 = tx*w01, b10 = tx*w10, b11 = tx*w11;
    float f0, f1;
    f0  = a00*q00.x;            f1  = a00*q00.y;
    f0  = fmaf(a01, q00.z, f0); f1  = fmaf(a01, q00.w, f1);
    f0  = fmaf(a10, q01.x, f0); f1  = fmaf(a10, q01.y, f1);
    f0  = fmaf(a11, q01.z, f0); f1  = fmaf(a11, q01.w, f1);
    f0  = fmaf(b00, q10.x, f0); f1  = fmaf(b00, q10.y, f1);
    f0  = fmaf(b01, q10.z, f0); f1  = fmaf(b01, q10.w, f1);
    f0  = fmaf(b10, q11.x, f0); f1  = fmaf(b10, q11.y, f1);
    f0  = fmaf(b11, q11.z, f0); f1  = fmaf(b11, q11.w, f1);
    return make_float2(f0, f1);
}

// relu(acc f32x16 D-tile) -> two B fragments (k-steps 0 and 1) for next layer
__device__ __forceinline__ void marshal_h(const f32x16& acc, short8& k0, short8& k1) {
    int q[8];
    #pragma unroll
    for (int j = 0; j < 8; ++j) {
        float lo = fmaxf(acc[2*j],   0.0f);
        float hi = fmaxf(acc[2*j+1], 0.0f);
        q[j] = cvt_pk(lo, hi);
    }
    int a0 = q[0], b0 = q[2]; SWAP32(a0, b0);
    int a1 = q[1], b1 = q[3]; SWAP32(a1, b1);
    int a2 = q[4], b2 = q[6]; SWAP32(a2, b2);
    int a3 = q[5], b3 = q[7]; SWAP32(a3, b3);
    S8 u0; u0.d[0] = a0; u0.d[1] = a1; u0.d[2] = b0; u0.d[3] = b1; k0 = u0.v;
    S8 u1; u1.d[0] = a2; u1.d[1] = a3; u1.d[2] = b2; u1.d[3] = b3; k1 = u1.v;
}

__global__ __launch_bounds__(256) void prep_kernel(
    const float* __restrict__ table, unsigned int* __restrict__ ws) {
    int i = blockIdx.x * blockDim.x + threadIdx.x;
    if (i < NTAB) {
        float2 t = reinterpret_cast<const float2*>(table)[i];
        ws[i] = (unsigned int)cvt_pk(t.x, t.y);
    }
}

template<bool USE_WS>
__global__ __launch_bounds__(512) void mlptex_kernel(
    const float* __restrict__ texc,
    const float* __restrict__ table,   // [533601,2] fp32
    const unsigned int* __restrict__ wsb, // packed-bf16 table (if USE_WS)
    const float* __restrict__ W0,      // [32,10]
    const float* __restrict__ W1,      // [32,32]
    const float* __restrict__ W2,      // [3,32]
    const float* __restrict__ minv,
    const float* __restrict__ maxv,
    float* __restrict__ out,           // [N,3]
    int N)
{
    extern __shared__ unsigned int lds[];   // NSTAGE packed-bf16 entries

    const float2* tab2 = reinterpret_cast<const float2*>(table);

    // ---- stage levels 0+1 into LDS (coalesced fp32 read, bf16-pack) ----
    for (int k = threadIdx.x; k < NSTAGE; k += 512) {
        float2 t = tab2[k];
        lds[k] = (unsigned int)cvt_pk(t.x, t.y);
    }

    const int tid  = blockIdx.x * blockDim.x + threadIdx.x;
    const int lane = threadIdx.x & 63;
    const int pt   = min(tid, N - 1);
    const bool live = (tid < N);

    const int row = lane & 31;
    const int kb  = lane >> 5;

    // ---- per-thread weight fragments (A operands, bf16) ----
    short8 w0f, w1f0, w1f1;
    {
        const float* p0 = W0 + row * 10;
        float4 a, b;
        if (kb == 0) {
            float2 f0 = *(const float2*)(p0 + 0);
            float2 f1 = *(const float2*)(p0 + 2);
            float2 f2 = *(const float2*)(p0 + 4);
            float2 f3 = *(const float2*)(p0 + 6);
            a = make_float4(f0.x, f0.y, f1.x, f1.y);
            b = make_float4(f2.x, f2.y, f3.x, f3.y);
        } else {
            float2 f4 = *(const float2*)(p0 + 8);
            a = make_float4(f4.x, f4.y, 0.f, 0.f);
            b = make_float4(0.f, 0.f, 0.f, 0.f);
        }
        w0f = pack8(a, b);

        const float* p1 = W1 + row * 32 + kb * 8;
        w1f0 = pack8(*(const float4*)(p1),      *(const float4*)(p1 + 4));
        w1f1 = pack8(*(const float4*)(p1 + 16), *(const float4*)(p1 + 20));
    }
    short8 w2f0 = {0,0,0,0,0,0,0,0}, w2f1 = {0,0,0,0,0,0,0,0};
    if (row < 3) {
        const float* p2 = W2 + row * 32 + kb * 8;
        w2f0 = pack8(*(const float4*)(p2),      *(const float4*)(p2 + 4));
        w2f1 = pack8(*(const float4*)(p2 + 16), *(const float4*)(p2 + 20));
    }

    // ---- coords (nontemporal: don't pollute L2) ----
    const float* tp = texc + 3 * pt;
    float x = __builtin_nontemporal_load(tp + 0);
    float y = __builtin_nontemporal_load(tp + 1);
    float z = __builtin_nontemporal_load(tp + 2);
    x = clamp01((x - 0.6f) * (-1.0f/1.4f));
    y = clamp01((y - 0.6f) * (-1.0f/1.8f));
    z = clamp01((z - 0.2f) * (-1.0f/0.4f));

    __syncthreads();   // LDS table ready

    const int RESL[5]  = {16, 23, 33, 48, 70};
    const int OFFSL[5] = {0, 4913, 18737, 58041, 175690};

    float pf[10];
    #pragma unroll
    for (int l = 0; l < 5; ++l) {
        const int r = RESL[l];
        const int g = r + 1;
        const int gg = g * g;
        const float rf = (float)r;
        float px = x * rf, py = y * rf, pz = z * rf;
        float fx = fminf(floorf(px), rf - 1.0f);
        float fy = fminf(floorf(py), rf - 1.0f);
        float fz = fminf(floorf(pz), rf - 1.0f);
        float tx = px - fx, ty = py - fy, tz = pz - fz;
        int ix = (int)fx & 127, iy = (int)fy & 127, iz = (int)fz & 127;
        int base = (ix * g + iy) * g + iz + OFFSL[l];

        float4 q00, q01, q10, q11;
        if (l < 2) {
            q00 = pair_lds(lds, base);
            q01 = pair_lds(lds, base + g);
            q10 = pair_lds(lds, base + gg);
            q11 = pair_lds(lds, base + gg + g);
        } else {
            if constexpr (USE_WS) {
                q00 = pair_ws(wsb, base);
                q01 = pair_ws(wsb, base + g);
                q10 = pair_ws(wsb, base + gg);
                q11 = pair_ws(wsb, base + gg + g);
            } else {
                q00 = pair_f32(tab2, base);
                q01 = pair_f32(tab2, base + g);
                q10 = pair_f32(tab2, base + gg);
                q11 = pair_f32(tab2, base + gg + g);
            }
        }
        float2 f = trilerp(tx, ty, tz, q00, q01, q10, q11);
        pf[2*l+0] = f.x;
        pf[2*l+1] = f.y;
    }

    // ---- features -> layer-0 B fragments for both 32-point tiles ----
    int pk0 = cvt_pk(pf[0], pf[1]);
    int pk1 = cvt_pk(pf[2], pf[3]);
    int pk2 = cvt_pk(pf[4], pf[5]);
    int pk3 = cvt_pk(pf[6], pf[7]);
    int pk4 = cvt_pk(pf[8], pf[9]);

    int n1d0 = pk0, n2d0 = pk4; SWAP32(n1d0, n2d0);
    int n1d1 = pk1, n2d1 = 0;   SWAP32(n1d1, n2d1);
    int n1d2 = pk2, n2d2 = 0;   SWAP32(n1d2, n2d2);
    int n1d3 = pk3, n2d3 = 0;   SWAP32(n1d3, n2d3);
    S8 ub1; ub1.d[0]=n1d0; ub1.d[1]=n1d1; ub1.d[2]=n1d2; ub1.d[3]=n1d3;
    S8 ub2; ub2.d[0]=n2d0; ub2.d[1]=n2d1; ub2.d[2]=n2d2; ub2.d[3]=n2d3;

    const f32x16 zero16 = {0.f,0.f,0.f,0.f,0.f,0.f,0.f,0.f,
                           0.f,0.f,0.f,0.f,0.f,0.f,0.f,0.f};

    // ---- layer 0 ----
    f32x16 h0a = __builtin_amdgcn_mfma_f32_32x32x16_bf16(w0f, ub1.v, zero16, 0, 0, 0);
    f32x16 h0b = __builtin_amdgcn_mfma_f32_32x32x16_bf16(w0f, ub2.v, zero16, 0, 0, 0);

    // ---- layer 1 ----
    short8 h0a_k0, h0a_k1, h0b_k0, h0b_k1;
    marshal_h(h0a, h0a_k0, h0a_k1);
    marshal_h(h0b, h0b_k0, h0b_k1);

    f32x16 h1a = __builtin_amdgcn_mfma_f32_32x32x16_bf16(w1f0, h0a_k0, zero16, 0, 0, 0);
    h1a = __builtin_amdgcn_mfma_f32_32x32x16_bf16(w1f1, h0a_k1, h1a, 0, 0, 0);
    f32x16 h1b = __builtin_amdgcn_mfma_f32_32x32x16_bf16(w1f0, h0b_k0, zero16, 0, 0, 0);
    h1b = __builtin_amdgcn_mfma_f32_32x32x16_bf16(w1f1, h0b_k1, h1b, 0, 0, 0);

    // ---- layer 2 ----
    short8 h1a_k0, h1a_k1, h1b_k0, h1b_k1;
    marshal_h(h1a, h1a_k0, h1a_k1);
    marshal_h(h1b, h1b_k0, h1b_k1);

    f32x16 oa = __builtin_amdgcn_mfma_f32_32x32x16_bf16(w2f0, h1a_k0, zero16, 0, 0, 0);
    oa = __builtin_amdgcn_mfma_f32_32x32x16_bf16(w2f1, h1a_k1, oa, 0, 0, 0);
    f32x16 ob = __builtin_amdgcn_mfma_f32_32x32x16_bf16(w2f0, h1b_k0, zero16, 0, 0, 0);
    ob = __builtin_amdgcn_mfma_f32_32x32x16_bf16(w2f1, h1b_k1, ob, 0, 0, 0);

    // ---- epilogue ----
    float mn[3] = {minv[0], minv[1], minv[2]};
    float sc[3] = {maxv[0] - minv[0], maxv[1] - minv[1], maxv[2] - minv[2]};

    float o[3];
    #pragma unroll
    for (int j = 0; j < 3; ++j) {
        float t0 = ob[j], t1 = ob[j];
        SWAP32(t0, t1);                       // upper lanes get partner's ob[j]
        float v = (lane < 32) ? oa[j] : t0;
        float s = 1.0f / (1.0f + __expf(-v));
        o[j] = fmaf(s, sc[j], mn[j]);
    }

    if (live) {
        float* op = out + 3 * tid;
        __builtin_nontemporal_store(o[0], op + 0);
        __builtin_nontemporal_store(o[1], op + 1);
        __builtin_nontemporal_store(o[2], op + 2);
    }
}

} // anonymous namespace

extern "C" void kernel_launch(void* const* d_in, const int* in_sizes, int n_in,
                              void* d_out, int out_size, void* d_ws, size_t ws_size,
                              hipStream_t stream) {
    const float* texc  = (const float*)d_in[0];
    const float* table = (const float*)d_in[1];
    const float* W0    = (const float*)d_in[2];
    const float* W1    = (const float*)d_in[3];
    const float* W2    = (const float*)d_in[4];
    const float* minv  = (const float*)d_in[5];
    const float* maxv  = (const float*)d_in[6];
    float* out = (float*)d_out;

    const int N = in_sizes[0] / 3;   // 4,194,304 points
    const int threads = 512;
    const int blocks = (N + threads - 1) / threads;
    const int smem = NSTAGE * 4;     // 74,948 B dynamic LDS

    const bool use_ws = ws_size >= (size_t)NTAB * 4u;

    if (use_ws) {
        unsigned int* wsb = (unsigned int*)d_ws;
        (void)hipFuncSetAttribute((const void*)&mlptex_kernel<true>,
                                  hipFuncAttributeMaxDynamicSharedMemorySize, smem);
        prep_kernel<<<(NTAB + 255) / 256, 256, 0, stream>>>(table, wsb);
        mlptex_kernel<true><<<blocks, threads, smem, stream>>>(
            texc, table, wsb, W0, W1, W2, minv, maxv, out, N);
    } else {
        (void)hipFuncSetAttribute((const void*)&mlptex_kernel<false>,
                                  hipFuncAttributeMaxDynamicSharedMemorySize, smem);
        mlptex_kernel<false><<<blocks, threads, smem, stream>>>(
            texc, table, nullptr, W0, W1, W2, minv, maxv, out, N);
    }
}

// Round 5
// 221.996 us; speedup vs baseline: 1.5458x; 1.5458x over previous
//
#include <hip/hip_runtime.h>
#include <hip/hip_bf16.h>
#include <math.h>

// MLPTexture3D: 5-level dense-grid trilinear encoding + MLP 10->32->32->3
// via v_mfma_f32_32x32x16_bf16 (64 points/wave).
//
// Round-5: gathers are bound by divergent-address request processing
// (per-lane TA serialization + L2 request count), NOT bytes/instr count
// (rounds 1-4 evidence). Fix: prep kernel rebuilds the table CELL-PACKED
// in d_ws -- the 8 corners of each cell as 32 contiguous bytes (bf16
// pairs). Main kernel: 2 dwordx4 gathers per level (10/point, was 20),
// both in ONE 64B line per cell (5 line-requests/point, was ~20).
// No LDS staging (round-4 regression).

namespace {

typedef __attribute__((ext_vector_type(8)))  short short8;
typedef __attribute__((ext_vector_type(16))) float f32x16;
typedef __attribute__((ext_vector_type(4), aligned(8))) float f32x4a;
typedef __attribute__((ext_vector_type(4), aligned(16))) unsigned int u32x4;

union S8 { short8 v; int d[4]; };

#define SWAP32(a, b) asm volatile("v_permlane32_swap_b32 %0, %1" : "+v"(a), "+v"(b))

constexpr int RES0 = 16, RES1 = 23, RES2 = 33, RES3 = 48, RES4 = 70;
// fp32-table level offsets (grid points, (r+1)^3)
constexpr int TOFF0 = 0, TOFF1 = 4913, TOFF2 = 18737, TOFF3 = 58041, TOFF4 = 175690;
// cell-table level offsets (cells, r^3)
constexpr int COFF0 = 0;
constexpr int COFF1 = COFF0 + RES0*RES0*RES0;          // 4096
constexpr int COFF2 = COFF1 + RES1*RES1*RES1;          // 16263
constexpr int COFF3 = COFF2 + RES2*RES2*RES2;          // 52200
constexpr int COFF4 = COFF3 + RES3*RES3*RES3;          // 162792
constexpr int NCELL = COFF4 + RES4*RES4*RES4;          // 505792
// ws bytes needed: NCELL * 32
constexpr size_t WS_NEED = (size_t)NCELL * 32u;

__device__ __forceinline__ int cvt_pk(float lo, float hi) {
    int d;
    asm("v_cvt_pk_bf16_f32 %0, %1, %2" : "=v"(d) : "v"(lo), "v"(hi));
    return d;
}

__device__ __forceinline__ short8 pack8(float4 a, float4 b) {
    S8 u;
    u.d[0] = cvt_pk(a.x, a.y);
    u.d[1] = cvt_pk(a.z, a.w);
    u.d[2] = cvt_pk(b.x, b.y);
    u.d[3] = cvt_pk(b.z, b.w);
    return u.v;
}

__device__ __forceinline__ float clamp01(float v) {
    return fminf(fmaxf(v, 0.0f), 1.0f);
}

__device__ __forceinline__ float2 upk(unsigned int u) {
    float2 r;
    r.x = __uint_as_float(u << 16);
    r.y = __uint_as_float(u & 0xffff0000u);
    return r;
}

// relu(acc f32x16 D-tile) -> two B fragments (k-steps 0 and 1) for next layer
__device__ __forceinline__ void marshal_h(const f32x16& acc, short8& k0, short8& k1) {
    int q[8];
    #pragma unroll
    for (int j = 0; j < 8; ++j) {
        float lo = fmaxf(acc[2*j],   0.0f);
        float hi = fmaxf(acc[2*j+1], 0.0f);
        q[j] = cvt_pk(lo, hi);
    }
    int a0 = q[0], b0 = q[2]; SWAP32(a0, b0);
    int a1 = q[1], b1 = q[3]; SWAP32(a1, b1);
    int a2 = q[4], b2 = q[6]; SWAP32(a2, b2);
    int a3 = q[5], b3 = q[7]; SWAP32(a3, b3);
    S8 u0; u0.d[0] = a0; u0.d[1] = a1; u0.d[2] = b0; u0.d[3] = b1; k0 = u0.v;
    S8 u1; u1.d[0] = a2; u1.d[1] = a3; u1.d[2] = b2; u1.d[3] = b3; k1 = u1.v;
}

// ---- prep: build cell-packed bf16 table in ws ----
// cell entry (32B): u32[8] = bf16pair at corners
// (dy,dz,dx order below: c[0]=000 c[1]=001 c[2]=010 c[3]=011, +x: c[4..7])
__global__ __launch_bounds__(256) void prep_kernel(
    const float* __restrict__ table, unsigned int* __restrict__ ws)
{
    int ci = blockIdx.x * blockDim.x + threadIdx.x;
    if (ci >= NCELL) return;

    int r, toff, c0;
    if      (ci < COFF1) { r = RES0; toff = TOFF0; c0 = COFF0; }
    else if (ci < COFF2) { r = RES1; toff = TOFF1; c0 = COFF1; }
    else if (ci < COFF3) { r = RES2; toff = TOFF2; c0 = COFF2; }
    else if (ci < COFF4) { r = RES3; toff = TOFF3; c0 = COFF3; }
    else                 { r = RES4; toff = TOFF4; c0 = COFF4; }

    int lc = ci - c0;
    int cz = lc % r;
    int t  = lc / r;
    int cy = t % r;
    int cx = t / r;
    int g  = r + 1;

    const float2* tab2 = reinterpret_cast<const float2*>(table);
    int base = (cx * g + cy) * g + cz + toff;

    unsigned int* dst = ws + (size_t)ci * 8;
    #pragma unroll
    for (int dx = 0; dx < 2; ++dx) {
        #pragma unroll
        for (int dy = 0; dy < 2; ++dy) {
            #pragma unroll
            for (int dz = 0; dz < 2; ++dz) {
                float2 v = tab2[base + (dx * g + dy) * g + dz];
                dst[dx*4 + dy*2 + dz] = (unsigned int)cvt_pk(v.x, v.y);
            }
        }
    }
}

template<bool USE_WS>
__global__ __launch_bounds__(512) void mlptex_kernel(
    const float* __restrict__ texc,
    const float* __restrict__ table,       // [533601,2] fp32 (fallback path)
    const unsigned int* __restrict__ cells, // cell-packed bf16 (if USE_WS)
    const float* __restrict__ W0,
    const float* __restrict__ W1,
    const float* __restrict__ W2,
    const float* __restrict__ minv,
    const float* __restrict__ maxv,
    float* __restrict__ out,
    int N)
{
    const int tid  = blockIdx.x * blockDim.x + threadIdx.x;
    const int lane = threadIdx.x & 63;
    const int pt   = min(tid, N - 1);
    const bool live = (tid < N);

    const int row = lane & 31;
    const int kb  = lane >> 5;

    // ---- per-thread weight fragments (A operands, bf16) ----
    short8 w0f, w1f0, w1f1;
    {
        const float* p0 = W0 + row * 10;
        float4 a, b;
        if (kb == 0) {
            float2 f0 = *(const float2*)(p0 + 0);
            float2 f1 = *(const float2*)(p0 + 2);
            float2 f2 = *(const float2*)(p0 + 4);
            float2 f3 = *(const float2*)(p0 + 6);
            a = make_float4(f0.x, f0.y, f1.x, f1.y);
            b = make_float4(f2.x, f2.y, f3.x, f3.y);
        } else {
            float2 f4 = *(const float2*)(p0 + 8);
            a = make_float4(f4.x, f4.y, 0.f, 0.f);
            b = make_float4(0.f, 0.f, 0.f, 0.f);
        }
        w0f = pack8(a, b);

        const float* p1 = W1 + row * 32 + kb * 8;
        w1f0 = pack8(*(const float4*)(p1),      *(const float4*)(p1 + 4));
        w1f1 = pack8(*(const float4*)(p1 + 16), *(const float4*)(p1 + 20));
    }
    short8 w2f0 = {0,0,0,0,0,0,0,0}, w2f1 = {0,0,0,0,0,0,0,0};
    if (row < 3) {
        const float* p2 = W2 + row * 32 + kb * 8;
        w2f0 = pack8(*(const float4*)(p2),      *(const float4*)(p2 + 4));
        w2f1 = pack8(*(const float4*)(p2 + 16), *(const float4*)(p2 + 20));
    }

    // ---- coords ----
    const float* tp = texc + 3 * pt;
    float x = __builtin_nontemporal_load(tp + 0);
    float y = __builtin_nontemporal_load(tp + 1);
    float z = __builtin_nontemporal_load(tp + 2);
    x = clamp01((x - 0.6f) * (-1.0f/1.4f));
    y = clamp01((y - 0.6f) * (-1.0f/1.8f));
    z = clamp01((z - 0.2f) * (-1.0f/0.4f));

    const int RESL[5]  = {RES0, RES1, RES2, RES3, RES4};
    const int TOFFL[5] = {TOFF0, TOFF1, TOFF2, TOFF3, TOFF4};
    const int COFFL[5] = {COFF0, COFF1, COFF2, COFF3, COFF4};
    const float2* tab2 = reinterpret_cast<const float2*>(table);

    float pf[10];
    #pragma unroll
    for (int l = 0; l < 5; ++l) {
        const int r = RESL[l];
        const int g = r + 1;
        const float rf = (float)r;
        float px = x * rf, py = y * rf, pz = z * rf;
        float fx = fminf(floorf(px), rf - 1.0f);
        float fy = fminf(floorf(py), rf - 1.0f);
        float fz = fminf(floorf(pz), rf - 1.0f);
        float tx = px - fx, ty = py - fy, tz = pz - fz;
        int ix = (int)fx & 127, iy = (int)fy & 127, iz = (int)fz & 127;

        float sx = 1.0f - tx, sy = 1.0f - ty, sz = 1.0f - tz;
        float w00 = sy*sz, w01 = sy*tz, w10 = ty*sz, w11 = ty*tz;
        float a00 = sx*w00, a01 = sx*w01, a10 = sx*w10, a11 = sx*w11;
        float b00 = tx*w00, b01 = tx*w01, b10 = tx*w10, b11 = tx*w11;

        float f0, f1;
        if constexpr (USE_WS) {
            // one 32B-aligned cell: 2 dwordx4 in the same 64B line
            int ci = (ix * r + iy) * r + iz + COFFL[l];
            const u32x4* cp = reinterpret_cast<const u32x4*>(cells + (size_t)ci * 8);
            u32x4 lo = cp[0];   // c000 c001 c010 c011
            u32x4 hi = cp[1];   // c100 c101 c110 c111
            float2 c000 = upk(lo.x), c001 = upk(lo.y), c010 = upk(lo.z), c011 = upk(lo.w);
            float2 c100 = upk(hi.x), c101 = upk(hi.y), c110 = upk(hi.z), c111 = upk(hi.w);
            f0  = a00*c000.x;            f1  = a00*c000.y;
            f0  = fmaf(a01, c001.x, f0); f1  = fmaf(a01, c001.y, f1);
            f0  = fmaf(a10, c010.x, f0); f1  = fmaf(a10, c010.y, f1);
            f0  = fmaf(a11, c011.x, f0); f1  = fmaf(a11, c011.y, f1);
            f0  = fmaf(b00, c100.x, f0); f1  = fmaf(b00, c100.y, f1);
            f0  = fmaf(b01, c101.x, f0); f1  = fmaf(b01, c101.y, f1);
            f0  = fmaf(b10, c110.x, f0); f1  = fmaf(b10, c110.y, f1);
            f0  = fmaf(b11, c111.x, f0); f1  = fmaf(b11, c111.y, f1);
        } else {
            const int gg = g * g;
            int base = (ix * g + iy) * g + iz + TOFFL[l];
            f32x4a q00 = *reinterpret_cast<const f32x4a*>(tab2 + base);
            f32x4a q01 = *reinterpret_cast<const f32x4a*>(tab2 + base + g);
            f32x4a q10 = *reinterpret_cast<const f32x4a*>(tab2 + base + gg);
            f32x4a q11 = *reinterpret_cast<const f32x4a*>(tab2 + base + gg + g);
            f0  = a00*q00[0];            f1  = a00*q00[1];
            f0  = fmaf(a01, q00[2], f0); f1  = fmaf(a01, q00[3], f1);
            f0  = fmaf(a10, q01[0], f0); f1  = fmaf(a10, q01[1], f1);
            f0  = fmaf(a11, q01[2], f0); f1  = fmaf(a11, q01[3], f1);
            f0  = fmaf(b00, q10[0], f0); f1  = fmaf(b00, q10[1], f1);
            f0  = fmaf(b01, q10[2], f0); f1  = fmaf(b01, q10[3], f1);
            f0  = fmaf(b10, q11[0], f0); f1  = fmaf(b10, q11[1], f1);
            f0  = fmaf(b11, q11[2], f0); f1  = fmaf(b11, q11[3], f1);
        }
        pf[2*l+0] = f0;
        pf[2*l+1] = f1;
    }

    // ---- features -> layer-0 B fragments ----
    int pk0 = cvt_pk(pf[0], pf[1]);
    int pk1 = cvt_pk(pf[2], pf[3]);
    int pk2 = cvt_pk(pf[4], pf[5]);
    int pk3 = cvt_pk(pf[6], pf[7]);
    int pk4 = cvt_pk(pf[8], pf[9]);

    int n1d0 = pk0, n2d0 = pk4; SWAP32(n1d0, n2d0);
    int n1d1 = pk1, n2d1 = 0;   SWAP32(n1d1, n2d1);
    int n1d2 = pk2, n2d2 = 0;   SWAP32(n1d2, n2d2);
    int n1d3 = pk3, n2d3 = 0;   SWAP32(n1d3, n2d3);
    S8 ub1; ub1.d[0]=n1d0; ub1.d[1]=n1d1; ub1.d[2]=n1d2; ub1.d[3]=n1d3;
    S8 ub2; ub2.d[0]=n2d0; ub2.d[1]=n2d1; ub2.d[2]=n2d2; ub2.d[3]=n2d3;

    const f32x16 zero16 = {0.f,0.f,0.f,0.f,0.f,0.f,0.f,0.f,
                           0.f,0.f,0.f,0.f,0.f,0.f,0.f,0.f};

    // ---- layer 0 ----
    f32x16 h0a = __builtin_amdgcn_mfma_f32_32x32x16_bf16(w0f, ub1.v, zero16, 0, 0, 0);
    f32x16 h0b = __builtin_amdgcn_mfma_f32_32x32x16_bf16(w0f, ub2.v, zero16, 0, 0, 0);

    // ---- layer 1 ----
    short8 h0a_k0, h0a_k1, h0b_k0, h0b_k1;
    marshal_h(h0a, h0a_k0, h0a_k1);
    marshal_h(h0b, h0b_k0, h0b_k1);

    f32x16 h1a = __builtin_amdgcn_mfma_f32_32x32x16_bf16(w1f0, h0a_k0, zero16, 0, 0, 0);
    h1a = __builtin_amdgcn_mfma_f32_32x32x16_bf16(w1f1, h0a_k1, h1a, 0, 0, 0);
    f32x16 h1b = __builtin_amdgcn_mfma_f32_32x32x16_bf16(w1f0, h0b_k0, zero16, 0, 0, 0);
    h1b = __builtin_amdgcn_mfma_f32_32x32x16_bf16(w1f1, h0b_k1, h1b, 0, 0, 0);

    // ---- layer 2 ----
    short8 h1a_k0, h1a_k1, h1b_k0, h1b_k1;
    marshal_h(h1a, h1a_k0, h1a_k1);
    marshal_h(h1b, h1b_k0, h1b_k1);

    f32x16 oa = __builtin_amdgcn_mfma_f32_32x32x16_bf16(w2f0, h1a_k0, zero16, 0, 0, 0);
    oa = __builtin_amdgcn_mfma_f32_32x32x16_bf16(w2f1, h1a_k1, oa, 0, 0, 0);
    f32x16 ob = __builtin_amdgcn_mfma_f32_32x32x16_bf16(w2f0, h1b_k0, zero16, 0, 0, 0);
    ob = __builtin_amdgcn_mfma_f32_32x32x16_bf16(w2f1, h1b_k1, ob, 0, 0, 0);

    // ---- epilogue ----
    float mn[3] = {minv[0], minv[1], minv[2]};
    float sc[3] = {maxv[0] - minv[0], maxv[1] - minv[1], maxv[2] - minv[2]};

    float o[3];
    #pragma unroll
    for (int j = 0; j < 3; ++j) {
        float t0 = ob[j], t1 = ob[j];
        SWAP32(t0, t1);
        float v = (lane < 32) ? oa[j] : t0;
        float s = 1.0f / (1.0f + __expf(-v));
        o[j] = fmaf(s, sc[j], mn[j]);
    }

    if (live) {
        float* op = out + 3 * tid;
        __builtin_nontemporal_store(o[0], op + 0);
        __builtin_nontemporal_store(o[1], op + 1);
        __builtin_nontemporal_store(o[2], op + 2);
    }
}

} // anonymous namespace

extern "C" void kernel_launch(void* const* d_in, const int* in_sizes, int n_in,
                              void* d_out, int out_size, void* d_ws, size_t ws_size,
                              hipStream_t stream) {
    const float* texc  = (const float*)d_in[0];
    const float* table = (const float*)d_in[1];
    const float* W0    = (const float*)d_in[2];
    const float* W1    = (const float*)d_in[3];
    const float* W2    = (const float*)d_in[4];
    const float* minv  = (const float*)d_in[5];
    const float* maxv  = (const float*)d_in[6];
    float* out = (float*)d_out;

    const int N = in_sizes[0] / 3;   // 4,194,304 points
    const int threads = 512;
    const int blocks = (N + threads - 1) / threads;

    if (ws_size >= WS_NEED) {
        unsigned int* cells = (unsigned int*)d_ws;
        prep_kernel<<<(NCELL + 255) / 256, 256, 0, stream>>>(table, cells);
        mlptex_kernel<true><<<blocks, threads, 0, stream>>>(
            texc, table, cells, W0, W1, W2, minv, maxv, out, N);
    } else {
        mlptex_kernel<false><<<blocks, threads, 0, stream>>>(
            texc, table, nullptr, W0, W1, W2, minv, maxv, out, N);
    }
}

// Round 6
// 204.121 us; speedup vs baseline: 1.6811x; 1.0876x over previous
//
#include <hip/hip_runtime.h>
#include <hip/hip_bf16.h>
#include <math.h>

// MLPTexture3D: 5-level dense-grid trilinear encoding + MLP 10->32->32->3
// via v_mfma_f32_32x32x16_bf16 (64 points/wave-tile).
//
// Round-6:
//  - prep kernel rewritten: per-level constant divisors (magic mul), 4x16B
//    vector loads, 2x coalesced nontemporal dwordx4 stores (was 94us: hw
//    idiv + 8 scalar gathers + 8 partial-line stores).
//  - main kernel: 2 points/thread (split-half streams) to amortize the
//    weight prologue and double independent chains (fills the 40% issue gap
//    seen at VALU 60% + MFMA 7%).

namespace {

typedef __attribute__((ext_vector_type(8)))  short short8;
typedef __attribute__((ext_vector_type(16))) float f32x16;
typedef __attribute__((ext_vector_type(4), aligned(8)))  float f32x4a;
typedef __attribute__((ext_vector_type(4), aligned(16))) unsigned int u32x4;

union S8 { short8 v; int d[4]; };

#define SWAP32(a, b) asm volatile("v_permlane32_swap_b32 %0, %1" : "+v"(a), "+v"(b))

constexpr int RES0 = 16, RES1 = 23, RES2 = 33, RES3 = 48, RES4 = 70;
constexpr int TOFF0 = 0, TOFF1 = 4913, TOFF2 = 18737, TOFF3 = 58041, TOFF4 = 175690;
constexpr int COFF0 = 0;
constexpr int COFF1 = COFF0 + RES0*RES0*RES0;
constexpr int COFF2 = COFF1 + RES1*RES1*RES1;
constexpr int COFF3 = COFF2 + RES2*RES2*RES2;
constexpr int COFF4 = COFF3 + RES3*RES3*RES3;
constexpr int NCELL = COFF4 + RES4*RES4*RES4;          // 505792
constexpr size_t WS_NEED = (size_t)NCELL * 32u;

__device__ __forceinline__ int cvt_pk(float lo, float hi) {
    int d;
    asm("v_cvt_pk_bf16_f32 %0, %1, %2" : "=v"(d) : "v"(lo), "v"(hi));
    return d;
}

__device__ __forceinline__ short8 pack8(float4 a, float4 b) {
    S8 u;
    u.d[0] = cvt_pk(a.x, a.y);
    u.d[1] = cvt_pk(a.z, a.w);
    u.d[2] = cvt_pk(b.x, b.y);
    u.d[3] = cvt_pk(b.z, b.w);
    return u.v;
}

__device__ __forceinline__ float clamp01(float v) {
    return fminf(fmaxf(v, 0.0f), 1.0f);
}

__device__ __forceinline__ float2 upk(unsigned int u) {
    float2 r;
    r.x = __uint_as_float(u << 16);
    r.y = __uint_as_float(u & 0xffff0000u);
    return r;
}

// relu(acc f32x16 D-tile) -> two B fragments (k-steps 0 and 1) for next layer
__device__ __forceinline__ void marshal_h(const f32x16& acc, short8& k0, short8& k1) {
    int q[8];
    #pragma unroll
    for (int j = 0; j < 8; ++j) {
        float lo = fmaxf(acc[2*j],   0.0f);
        float hi = fmaxf(acc[2*j+1], 0.0f);
        q[j] = cvt_pk(lo, hi);
    }
    int a0 = q[0], b0 = q[2]; SWAP32(a0, b0);
    int a1 = q[1], b1 = q[3]; SWAP32(a1, b1);
    int a2 = q[4], b2 = q[6]; SWAP32(a2, b2);
    int a3 = q[5], b3 = q[7]; SWAP32(a3, b3);
    S8 u0; u0.d[0] = a0; u0.d[1] = a1; u0.d[2] = b0; u0.d[3] = b1; k0 = u0.v;
    S8 u1; u1.d[0] = a2; u1.d[1] = a3; u1.d[2] = b2; u1.d[3] = b3; k1 = u1.v;
}

// ---- prep: build cell-packed bf16 table in ws ----
// cell entry (32B): u32[dx*4+dy*2+dz] = bf16 pair at that corner
template<int R, int TOFF, int COFF>
__device__ __forceinline__ void prep_level(int ci, const float2* __restrict__ tab2,
                                           unsigned int* __restrict__ ws)
{
    constexpr int G = R + 1;
    int lc = ci - COFF;                 // compile-time R -> magic-mul div
    int cz = lc % R;
    int t  = lc / R;
    int cy = t % R;
    int cx = t / R;
    int base = (cx * G + cy) * G + cz + TOFF;

    f32x4a q00 = *reinterpret_cast<const f32x4a*>(tab2 + base);            // c000 c001
    f32x4a q01 = *reinterpret_cast<const f32x4a*>(tab2 + base + G);        // c010 c011
    f32x4a q10 = *reinterpret_cast<const f32x4a*>(tab2 + base + G*G);      // c100 c101
    f32x4a q11 = *reinterpret_cast<const f32x4a*>(tab2 + base + G*G + G);  // c110 c111

    u32x4 lo, hi;
    lo.x = (unsigned int)cvt_pk(q00[0], q00[1]);
    lo.y = (unsigned int)cvt_pk(q00[2], q00[3]);
    lo.z = (unsigned int)cvt_pk(q01[0], q01[1]);
    lo.w = (unsigned int)cvt_pk(q01[2], q01[3]);
    hi.x = (unsigned int)cvt_pk(q10[0], q10[1]);
    hi.y = (unsigned int)cvt_pk(q10[2], q10[3]);
    hi.z = (unsigned int)cvt_pk(q11[0], q11[1]);
    hi.w = (unsigned int)cvt_pk(q11[2], q11[3]);

    u32x4* dst = reinterpret_cast<u32x4*>(ws + (size_t)ci * 8);
    __builtin_nontemporal_store(lo, dst);
    __builtin_nontemporal_store(hi, dst + 1);
}

__global__ __launch_bounds__(256) void prep_kernel(
    const float* __restrict__ table, unsigned int* __restrict__ ws)
{
    int ci = blockIdx.x * blockDim.x + threadIdx.x;
    const float2* tab2 = reinterpret_cast<const float2*>(table);
    if      (ci < COFF1) prep_level<RES0, TOFF0, COFF0>(ci, tab2, ws);
    else if (ci < COFF2) prep_level<RES1, TOFF1, COFF1>(ci, tab2, ws);
    else if (ci < COFF3) prep_level<RES2, TOFF2, COFF2>(ci, tab2, ws);
    else if (ci < COFF4) prep_level<RES3, TOFF3, COFF3>(ci, tab2, ws);
    else if (ci < NCELL) prep_level<RES4, TOFF4, COFF4>(ci, tab2, ws);
}

// ---- encoding: coords -> 10 features ----
template<bool USE_WS>
__device__ __forceinline__ void encode(float x, float y, float z,
    const unsigned int* __restrict__ cells, const float2* __restrict__ tab2,
    float* __restrict__ pf)
{
    const int RESL[5]  = {RES0, RES1, RES2, RES3, RES4};
    const int TOFFL[5] = {TOFF0, TOFF1, TOFF2, TOFF3, TOFF4};
    const int COFFL[5] = {COFF0, COFF1, COFF2, COFF3, COFF4};

    #pragma unroll
    for (int l = 0; l < 5; ++l) {
        const int r = RESL[l];
        const int g = r + 1;
        const float rf = (float)r;
        float px = x * rf, py = y * rf, pz = z * rf;
        float fx = fminf(floorf(px), rf - 1.0f);
        float fy = fminf(floorf(py), rf - 1.0f);
        float fz = fminf(floorf(pz), rf - 1.0f);
        float tx = px - fx, ty = py - fy, tz = pz - fz;
        int ix = (int)fx & 127, iy = (int)fy & 127, iz = (int)fz & 127;

        float sx = 1.0f - tx, sy = 1.0f - ty, sz = 1.0f - tz;
        float w00 = sy*sz, w01 = sy*tz, w10 = ty*sz, w11 = ty*tz;
        float a00 = sx*w00, a01 = sx*w01, a10 = sx*w10, a11 = sx*w11;
        float b00 = tx*w00, b01 = tx*w01, b10 = tx*w10, b11 = tx*w11;

        float f0, f1;
        if constexpr (USE_WS) {
            int ci = (ix * r + iy) * r + iz + COFFL[l];
            const u32x4* cp = reinterpret_cast<const u32x4*>(cells + (size_t)ci * 8);
            u32x4 lo = cp[0];
            u32x4 hi = cp[1];
            float2 c000 = upk(lo.x), c001 = upk(lo.y), c010 = upk(lo.z), c011 = upk(lo.w);
            float2 c100 = upk(hi.x), c101 = upk(hi.y), c110 = upk(hi.z), c111 = upk(hi.w);
            f0  = a00*c000.x;            f1  = a00*c000.y;
            f0  = fmaf(a01, c001.x, f0); f1  = fmaf(a01, c001.y, f1);
            f0  = fmaf(a10, c010.x, f0); f1  = fmaf(a10, c010.y, f1);
            f0  = fmaf(a11, c011.x, f0); f1  = fmaf(a11, c011.y, f1);
            f0  = fmaf(b00, c100.x, f0); f1  = fmaf(b00, c100.y, f1);
            f0  = fmaf(b01, c101.x, f0); f1  = fmaf(b01, c101.y, f1);
            f0  = fmaf(b10, c110.x, f0); f1  = fmaf(b10, c110.y, f1);
            f0  = fmaf(b11, c111.x, f0); f1  = fmaf(b11, c111.y, f1);
        } else {
            const int gg = g * g;
            int base = (ix * g + iy) * g + iz + TOFFL[l];
            f32x4a q00 = *reinterpret_cast<const f32x4a*>(tab2 + base);
            f32x4a q01 = *reinterpret_cast<const f32x4a*>(tab2 + base + g);
            f32x4a q10 = *reinterpret_cast<const f32x4a*>(tab2 + base + gg);
            f32x4a q11 = *reinterpret_cast<const f32x4a*>(tab2 + base + gg + g);
            f0  = a00*q00[0];            f1  = a00*q00[1];
            f0  = fmaf(a01, q00[2], f0); f1  = fmaf(a01, q00[3], f1);
            f0  = fmaf(a10, q01[0], f0); f1  = fmaf(a10, q01[1], f1);
            f0  = fmaf(a11, q01[2], f0); f1  = fmaf(a11, q01[3], f1);
            f0  = fmaf(b00, q10[0], f0); f1  = fmaf(b00, q10[1], f1);
            f0  = fmaf(b01, q10[2], f0); f1  = fmaf(b01, q10[3], f1);
            f0  = fmaf(b10, q11[0], f0); f1  = fmaf(b10, q11[1], f1);
            f0  = fmaf(b11, q11[2], f0); f1  = fmaf(b11, q11[3], f1);
        }
        pf[2*l+0] = f0;
        pf[2*l+1] = f1;
    }
}

// ---- MLP: 10 features -> pre-sigmoid outputs v[3] for this lane's point ----
__device__ __forceinline__ void run_mlp(const float* __restrict__ pf,
    short8 w0f, short8 w1f0, short8 w1f1, short8 w2f0, short8 w2f1,
    int lane, float* __restrict__ v)
{
    int pk0 = cvt_pk(pf[0], pf[1]);
    int pk1 = cvt_pk(pf[2], pf[3]);
    int pk2 = cvt_pk(pf[4], pf[5]);
    int pk3 = cvt_pk(pf[6], pf[7]);
    int pk4 = cvt_pk(pf[8], pf[9]);

    int n1d0 = pk0, n2d0 = pk4; SWAP32(n1d0, n2d0);
    int n1d1 = pk1, n2d1 = 0;   SWAP32(n1d1, n2d1);
    int n1d2 = pk2, n2d2 = 0;   SWAP32(n1d2, n2d2);
    int n1d3 = pk3, n2d3 = 0;   SWAP32(n1d3, n2d3);
    S8 ub1; ub1.d[0]=n1d0; ub1.d[1]=n1d1; ub1.d[2]=n1d2; ub1.d[3]=n1d3;
    S8 ub2; ub2.d[0]=n2d0; ub2.d[1]=n2d1; ub2.d[2]=n2d2; ub2.d[3]=n2d3;

    const f32x16 zero16 = {0.f,0.f,0.f,0.f,0.f,0.f,0.f,0.f,
                           0.f,0.f,0.f,0.f,0.f,0.f,0.f,0.f};

    f32x16 h0a = __builtin_amdgcn_mfma_f32_32x32x16_bf16(w0f, ub1.v, zero16, 0, 0, 0);
    f32x16 h0b = __builtin_amdgcn_mfma_f32_32x32x16_bf16(w0f, ub2.v, zero16, 0, 0, 0);

    short8 h0a_k0, h0a_k1, h0b_k0, h0b_k1;
    marshal_h(h0a, h0a_k0, h0a_k1);
    marshal_h(h0b, h0b_k0, h0b_k1);

    f32x16 h1a = __builtin_amdgcn_mfma_f32_32x32x16_bf16(w1f0, h0a_k0, zero16, 0, 0, 0);
    h1a = __builtin_amdgcn_mfma_f32_32x32x16_bf16(w1f1, h0a_k1, h1a, 0, 0, 0);
    f32x16 h1b = __builtin_amdgcn_mfma_f32_32x32x16_bf16(w1f0, h0b_k0, zero16, 0, 0, 0);
    h1b = __builtin_amdgcn_mfma_f32_32x32x16_bf16(w1f1, h0b_k1, h1b, 0, 0, 0);

    short8 h1a_k0, h1a_k1, h1b_k0, h1b_k1;
    marshal_h(h1a, h1a_k0, h1a_k1);
    marshal_h(h1b, h1b_k0, h1b_k1);

    f32x16 oa = __builtin_amdgcn_mfma_f32_32x32x16_bf16(w2f0, h1a_k0, zero16, 0, 0, 0);
    oa = __builtin_amdgcn_mfma_f32_32x32x16_bf16(w2f1, h1a_k1, oa, 0, 0, 0);
    f32x16 ob = __builtin_amdgcn_mfma_f32_32x32x16_bf16(w2f0, h1b_k0, zero16, 0, 0, 0);
    ob = __builtin_amdgcn_mfma_f32_32x32x16_bf16(w2f1, h1b_k1, ob, 0, 0, 0);

    #pragma unroll
    for (int j = 0; j < 3; ++j) {
        float t0 = ob[j], t1 = ob[j];
        SWAP32(t0, t1);
        v[j] = (lane < 32) ? oa[j] : t0;
    }
}

template<bool USE_WS>
__global__ __launch_bounds__(512) void mlptex_kernel(
    const float* __restrict__ texc,
    const float* __restrict__ table,
    const unsigned int* __restrict__ cells,
    const float* __restrict__ W0,
    const float* __restrict__ W1,
    const float* __restrict__ W2,
    const float* __restrict__ minv,
    const float* __restrict__ maxv,
    float* __restrict__ out,
    int N)
{
    const int H   = N >> 1;                       // two coalesced half-streams
    const int tid = blockIdx.x * blockDim.x + threadIdx.x;
    const int lane = threadIdx.x & 63;
    const int pt0 = min(tid, H - 1);
    const int pt1 = pt0 + H;
    const bool live = (tid < H);

    const int row = lane & 31;
    const int kb  = lane >> 5;

    // ---- per-thread weight fragments (A operands, bf16) ----
    short8 w0f, w1f0, w1f1;
    {
        const float* p0 = W0 + row * 10;
        float4 a, b;
        if (kb == 0) {
            float2 f0 = *(const float2*)(p0 + 0);
            float2 f1 = *(const float2*)(p0 + 2);
            float2 f2 = *(const float2*)(p0 + 4);
            float2 f3 = *(const float2*)(p0 + 6);
            a = make_float4(f0.x, f0.y, f1.x, f1.y);
            b = make_float4(f2.x, f2.y, f3.x, f3.y);
        } else {
            float2 f4 = *(const float2*)(p0 + 8);
            a = make_float4(f4.x, f4.y, 0.f, 0.f);
            b = make_float4(0.f, 0.f, 0.f, 0.f);
        }
        w0f = pack8(a, b);

        const float* p1 = W1 + row * 32 + kb * 8;
        w1f0 = pack8(*(const float4*)(p1),      *(const float4*)(p1 + 4));
        w1f1 = pack8(*(const float4*)(p1 + 16), *(const float4*)(p1 + 20));
    }
    short8 w2f0 = {0,0,0,0,0,0,0,0}, w2f1 = {0,0,0,0,0,0,0,0};
    if (row < 3) {
        const float* p2 = W2 + row * 32 + kb * 8;
        w2f0 = pack8(*(const float4*)(p2),      *(const float4*)(p2 + 4));
        w2f1 = pack8(*(const float4*)(p2 + 16), *(const float4*)(p2 + 20));
    }

    // ---- coords for both streams ----
    const float* ta = texc + 3 * pt0;
    const float* tb = texc + 3 * pt1;
    float x0 = __builtin_nontemporal_load(ta + 0);
    float y0 = __builtin_nontemporal_load(ta + 1);
    float z0 = __builtin_nontemporal_load(ta + 2);
    float x1 = __builtin_nontemporal_load(tb + 0);
    float y1 = __builtin_nontemporal_load(tb + 1);
    float z1 = __builtin_nontemporal_load(tb + 2);
    x0 = clamp01((x0 - 0.6f) * (-1.0f/1.4f));
    y0 = clamp01((y0 - 0.6f) * (-1.0f/1.8f));
    z0 = clamp01((z0 - 0.2f) * (-1.0f/0.4f));
    x1 = clamp01((x1 - 0.6f) * (-1.0f/1.4f));
    y1 = clamp01((y1 - 0.6f) * (-1.0f/1.8f));
    z1 = clamp01((z1 - 0.2f) * (-1.0f/0.4f));

    const float2* tab2 = reinterpret_cast<const float2*>(table);

    float pf0[10], pf1[10];
    encode<USE_WS>(x0, y0, z0, cells, tab2, pf0);
    encode<USE_WS>(x1, y1, z1, cells, tab2, pf1);

    float v0[3], v1[3];
    run_mlp(pf0, w0f, w1f0, w1f1, w2f0, w2f1, lane, v0);
    run_mlp(pf1, w0f, w1f0, w1f1, w2f0, w2f1, lane, v1);

    float mn[3] = {minv[0], minv[1], minv[2]};
    float sc[3] = {maxv[0] - minv[0], maxv[1] - minv[1], maxv[2] - minv[2]};

    if (live) {
        float* oa = out + 3 * pt0;
        float* ob = out + 3 * pt1;
        #pragma unroll
        for (int j = 0; j < 3; ++j) {
            float s0 = 1.0f / (1.0f + __expf(-v0[j]));
            float s1 = 1.0f / (1.0f + __expf(-v1[j]));
            __builtin_nontemporal_store(fmaf(s0, sc[j], mn[j]), oa + j);
            __builtin_nontemporal_store(fmaf(s1, sc[j], mn[j]), ob + j);
        }
    }
}

} // anonymous namespace

extern "C" void kernel_launch(void* const* d_in, const int* in_sizes, int n_in,
                              void* d_out, int out_size, void* d_ws, size_t ws_size,
                              hipStream_t stream) {
    const float* texc  = (const float*)d_in[0];
    const float* table = (const float*)d_in[1];
    const float* W0    = (const float*)d_in[2];
    const float* W1    = (const float*)d_in[3];
    const float* W2    = (const float*)d_in[4];
    const float* minv  = (const float*)d_in[5];
    const float* maxv  = (const float*)d_in[6];
    float* out = (float*)d_out;

    const int N = in_sizes[0] / 3;   // 4,194,304 points (even)
    const int threads = 512;
    const int blocks = ((N / 2) + threads - 1) / threads;

    if (ws_size >= WS_NEED) {
        unsigned int* cells = (unsigned int*)d_ws;
        prep_kernel<<<(NCELL + 255) / 256, 256, 0, stream>>>(table, cells);
        mlptex_kernel<true><<<blocks, threads, 0, stream>>>(
            texc, table, cells, W0, W1, W2, minv, maxv, out, N);
    } else {
        mlptex_kernel<false><<<blocks, threads, 0, stream>>>(
            texc, table, nullptr, W0, W1, W2, minv, maxv, out, N);
    }
}